// Round 1
// baseline (1800.206 us; speedup 1.0000x reference)
//
#include <hip/hip_runtime.h>
#include <hip/hip_bf16.h>
#include <math.h>

#define DIM 768
#define NH 12
#define HD 64
#define BATCH 2
#define SEQ 4096
#define MTOT (BATCH * SEQ)   // 8192

// ---------------------------------------------------------------------------
// GEMM1: C[8192,2304] = x[8192,768] @ Wqkv[768,2304] + bqkv, scattered into
// Q/K/V buffers laid out [B*NH][SEQ][HD].
// 128x128 tile, BK=16, 256 threads, 8x8 micro-tile per thread. fp32.
// ---------------------------------------------------------------------------
__global__ __launch_bounds__(256)
void gemm_qkv(const float* __restrict__ A, const float* __restrict__ W,
              const float* __restrict__ bias,
              float* __restrict__ Qb, float* __restrict__ Kb, float* __restrict__ Vb)
{
    const int m0 = blockIdx.x * 128;
    const int n0 = blockIdx.y * 128;
    __shared__ float As[16][132];   // [k][m], pad 132 (528B rows, 16B aligned)
    __shared__ float Bs[16][132];   // [k][n]
    const int t  = threadIdx.x;
    const int tx = t & 15, ty = t >> 4;

    float acc[8][8];
#pragma unroll
    for (int i = 0; i < 8; i++)
#pragma unroll
        for (int j = 0; j < 8; j++) acc[i][j] = 0.f;

    for (int k0 = 0; k0 < 768; k0 += 16) {
        // A tile: 128 rows x 16 cols = 512 float4
#pragma unroll
        for (int it = 0; it < 2; ++it) {
            int fid = t + 256 * it;
            int r = fid >> 2, cq = fid & 3;
            float4 v = *(const float4*)&A[(size_t)(m0 + r) * 768 + k0 + cq * 4];
            As[cq * 4 + 0][r] = v.x;
            As[cq * 4 + 1][r] = v.y;
            As[cq * 4 + 2][r] = v.z;
            As[cq * 4 + 3][r] = v.w;
        }
        // B tile: 16 rows x 128 cols = 512 float4
#pragma unroll
        for (int it = 0; it < 2; ++it) {
            int fid = t + 256 * it;
            int r = fid >> 5, c4 = fid & 31;
            float4 v = *(const float4*)&W[(size_t)(k0 + r) * 2304 + n0 + c4 * 4];
            *(float4*)&Bs[r][c4 * 4] = v;
        }
        __syncthreads();
#pragma unroll
        for (int k = 0; k < 16; k++) {
            float4 a0 = *(float4*)&As[k][ty * 4];
            float4 a1 = *(float4*)&As[k][64 + ty * 4];
            float4 b0 = *(float4*)&Bs[k][tx * 4];
            float4 b1 = *(float4*)&Bs[k][64 + tx * 4];
            float av[8] = {a0.x, a0.y, a0.z, a0.w, a1.x, a1.y, a1.z, a1.w};
            float bv[8] = {b0.x, b0.y, b0.z, b0.w, b1.x, b1.y, b1.z, b1.w};
#pragma unroll
            for (int i = 0; i < 8; i++)
#pragma unroll
                for (int j = 0; j < 8; j++)
                    acc[i][j] += av[i] * bv[j];
        }
        __syncthreads();
    }

    // epilogue: add bias, scatter to Q/K/V [b*NH+h][s][d]
#pragma unroll
    for (int i = 0; i < 8; i++) {
        int r = (i >> 2) * 64 + ty * 4 + (i & 3);
        int m = m0 + r;
        int b = m >> 12;        // /4096
        int s = m & 4095;
#pragma unroll
        for (int jh = 0; jh < 2; ++jh) {
            int n = n0 + jh * 64 + tx * 4;
            int three = n / 768;
            int rem = n - three * 768;
            int h = rem >> 6;
            int d = rem & 63;
            float4 v;
            v.x = acc[i][jh * 4 + 0] + bias[n + 0];
            v.y = acc[i][jh * 4 + 1] + bias[n + 1];
            v.z = acc[i][jh * 4 + 2] + bias[n + 2];
            v.w = acc[i][jh * 4 + 3] + bias[n + 3];
            float* dst = (three == 0) ? Qb : ((three == 1) ? Kb : Vb);
            *(float4*)&dst[(((size_t)(b * NH + h)) * SEQ + s) * HD + d] = v;
        }
    }
}

// ---------------------------------------------------------------------------
// Flash attention, fp32, causal. One block = one (b,h) x one 64-row Q tile.
// 256 threads; each thread owns 4x4 of the 64x64 score tile and 4x4 of the
// 64x64 O tile. K stored TRANSPOSED in LDS so all inner-loop reads are
// conflict-free float4. KPs buffer is reused for K^T (scores) then P (PV).
// ---------------------------------------------------------------------------
__global__ __launch_bounds__(256)
void flash_attn(const float* __restrict__ Qg, const float* __restrict__ Kg,
                const float* __restrict__ Vg, float* __restrict__ Og)
{
    const int qt = blockIdx.x;          // q tile (0..63)
    const int bh = blockIdx.y;          // 0..23
    const int qbase = qt * 64;
    const float scale = 0.125f;         // 1/sqrt(64)

    __shared__ float Qs[64][68];    // [q_row][feat]
    __shared__ float KPs[64][68];   // scores phase: [feat][key]; PV phase: [q_row][key]
    __shared__ float Vs[64][68];    // [key][feat]

    const int t  = threadIdx.x;
    const int tx = t & 15, ty = t >> 4;

    const float* Qp = Qg + (size_t)bh * SEQ * HD;
    const float* Kp = Kg + (size_t)bh * SEQ * HD;
    const float* Vp = Vg + (size_t)bh * SEQ * HD;

    // load Q tile once
#pragma unroll
    for (int it = 0; it < 4; ++it) {
        int fid = t + 256 * it;         // 0..1023
        int r = fid >> 4, c4 = fid & 15;
        *(float4*)&Qs[r][c4 * 4] = *(const float4*)&Qp[(size_t)(qbase + r) * HD + c4 * 4];
    }

    float o[4][4];
#pragma unroll
    for (int i = 0; i < 4; i++)
#pragma unroll
        for (int j = 0; j < 4; j++) o[i][j] = 0.f;
    float mrow[4] = {-INFINITY, -INFINITY, -INFINITY, -INFINITY};
    float lrow[4] = {0.f, 0.f, 0.f, 0.f};

    for (int tk = 0; tk <= qt; ++tk) {
        const int kbase = tk * 64;
        __syncthreads();   // prev iteration's PV reads done
        // load K (transposed into KPs) and V
#pragma unroll
        for (int it = 0; it < 4; ++it) {
            int fid = t + 256 * it;
            int r = fid >> 4, c4 = fid & 15;
            float4 kv = *(const float4*)&Kp[(size_t)(kbase + r) * HD + c4 * 4];
            KPs[c4 * 4 + 0][r] = kv.x;
            KPs[c4 * 4 + 1][r] = kv.y;
            KPs[c4 * 4 + 2][r] = kv.z;
            KPs[c4 * 4 + 3][r] = kv.w;
            *(float4*)&Vs[r][c4 * 4] = *(const float4*)&Vp[(size_t)(kbase + r) * HD + c4 * 4];
        }
        __syncthreads();

        // scores: s[i][j] = sum_k Q[ty*4+i][k] * K[tx*4+j][k]
        float s[4][4];
#pragma unroll
        for (int i = 0; i < 4; i++)
#pragma unroll
            for (int j = 0; j < 4; j++) s[i][j] = 0.f;
        for (int kk = 0; kk < 64; kk += 4) {
            float qa[4][4], kt[4][4];
#pragma unroll
            for (int i = 0; i < 4; i++) {
                float4 v = *(float4*)&Qs[ty * 4 + i][kk];
                qa[i][0] = v.x; qa[i][1] = v.y; qa[i][2] = v.z; qa[i][3] = v.w;
            }
#pragma unroll
            for (int k2 = 0; k2 < 4; k2++) {
                float4 v = *(float4*)&KPs[kk + k2][tx * 4];
                kt[k2][0] = v.x; kt[k2][1] = v.y; kt[k2][2] = v.z; kt[k2][3] = v.w;
            }
#pragma unroll
            for (int i = 0; i < 4; i++)
#pragma unroll
                for (int j = 0; j < 4; j++)
#pragma unroll
                    for (int k2 = 0; k2 < 4; k2++)
                        s[i][j] += qa[i][k2] * kt[k2][j];
        }

        // scale + causal mask (only diagonal tile has masked entries)
        const bool diag = (tk == qt);
#pragma unroll
        for (int i = 0; i < 4; i++)
#pragma unroll
            for (int j = 0; j < 4; j++) {
                float v = s[i][j] * scale;
                if (diag && (tx * 4 + j) > (ty * 4 + i)) v = -INFINITY;
                s[i][j] = v;
            }

        __syncthreads();   // done reading KPs as K^T, about to overwrite with P

        // online softmax update + write P into KPs
#pragma unroll
        for (int i = 0; i < 4; i++) {
            float rm = fmaxf(fmaxf(s[i][0], s[i][1]), fmaxf(s[i][2], s[i][3]));
#pragma unroll
            for (int off = 1; off < 16; off <<= 1)
                rm = fmaxf(rm, __shfl_xor(rm, off));
            float mnew = fmaxf(mrow[i], rm);
            float alpha = __expf(mrow[i] - mnew);
            float rs = 0.f;
#pragma unroll
            for (int j = 0; j < 4; j++) {
                float p = __expf(s[i][j] - mnew);
                s[i][j] = p;
                rs += p;
            }
#pragma unroll
            for (int off = 1; off < 16; off <<= 1)
                rs += __shfl_xor(rs, off);
            lrow[i] = lrow[i] * alpha + rs;
            mrow[i] = mnew;
#pragma unroll
            for (int j = 0; j < 4; j++) o[i][j] *= alpha;
            *(float4*)&KPs[ty * 4 + i][tx * 4] = make_float4(s[i][0], s[i][1], s[i][2], s[i][3]);
        }
        __syncthreads();   // P visible

        // PV: o[i][j] += sum_k P[ty*4+i][k] * V[k][tx*4+j]
        for (int kk = 0; kk < 64; kk += 4) {
            float pa[4][4], vb[4][4];
#pragma unroll
            for (int i = 0; i < 4; i++) {
                float4 v = *(float4*)&KPs[ty * 4 + i][kk];
                pa[i][0] = v.x; pa[i][1] = v.y; pa[i][2] = v.z; pa[i][3] = v.w;
            }
#pragma unroll
            for (int k2 = 0; k2 < 4; k2++) {
                float4 v = *(float4*)&Vs[kk + k2][tx * 4];
                vb[k2][0] = v.x; vb[k2][1] = v.y; vb[k2][2] = v.z; vb[k2][3] = v.w;
            }
#pragma unroll
            for (int i = 0; i < 4; i++)
#pragma unroll
                for (int j = 0; j < 4; j++)
#pragma unroll
                    for (int k2 = 0; k2 < 4; k2++)
                        o[i][j] += pa[i][k2] * vb[k2][j];
        }
    }

    // epilogue: normalize and write [b][q][h*64+d]
    const int b = bh / NH, h = bh % NH;
#pragma unroll
    for (int i = 0; i < 4; i++) {
        float inv = 1.f / lrow[i];
        int q = qbase + ty * 4 + i;
        float4 ov = make_float4(o[i][0] * inv, o[i][1] * inv, o[i][2] * inv, o[i][3] * inv);
        *(float4*)&Og[((size_t)(b * SEQ + q)) * DIM + h * HD + tx * 4] = ov;
    }
}

// ---------------------------------------------------------------------------
// GEMM3: out[8192,768] = Ao[8192,768] @ Wout[768,768] + bout
// ---------------------------------------------------------------------------
__global__ __launch_bounds__(256)
void gemm_out(const float* __restrict__ A, const float* __restrict__ W,
              const float* __restrict__ bias, float* __restrict__ C)
{
    const int m0 = blockIdx.x * 128;
    const int n0 = blockIdx.y * 128;
    __shared__ float As[16][132];
    __shared__ float Bs[16][132];
    const int t  = threadIdx.x;
    const int tx = t & 15, ty = t >> 4;

    float acc[8][8];
#pragma unroll
    for (int i = 0; i < 8; i++)
#pragma unroll
        for (int j = 0; j < 8; j++) acc[i][j] = 0.f;

    for (int k0 = 0; k0 < 768; k0 += 16) {
#pragma unroll
        for (int it = 0; it < 2; ++it) {
            int fid = t + 256 * it;
            int r = fid >> 2, cq = fid & 3;
            float4 v = *(const float4*)&A[(size_t)(m0 + r) * 768 + k0 + cq * 4];
            As[cq * 4 + 0][r] = v.x;
            As[cq * 4 + 1][r] = v.y;
            As[cq * 4 + 2][r] = v.z;
            As[cq * 4 + 3][r] = v.w;
        }
#pragma unroll
        for (int it = 0; it < 2; ++it) {
            int fid = t + 256 * it;
            int r = fid >> 5, c4 = fid & 31;
            float4 v = *(const float4*)&W[(size_t)(k0 + r) * 768 + n0 + c4 * 4];
            *(float4*)&Bs[r][c4 * 4] = v;
        }
        __syncthreads();
#pragma unroll
        for (int k = 0; k < 16; k++) {
            float4 a0 = *(float4*)&As[k][ty * 4];
            float4 a1 = *(float4*)&As[k][64 + ty * 4];
            float4 b0 = *(float4*)&Bs[k][tx * 4];
            float4 b1 = *(float4*)&Bs[k][64 + tx * 4];
            float av[8] = {a0.x, a0.y, a0.z, a0.w, a1.x, a1.y, a1.z, a1.w};
            float bv[8] = {b0.x, b0.y, b0.z, b0.w, b1.x, b1.y, b1.z, b1.w};
#pragma unroll
            for (int i = 0; i < 8; i++)
#pragma unroll
                for (int j = 0; j < 8; j++)
                    acc[i][j] += av[i] * bv[j];
        }
        __syncthreads();
    }

#pragma unroll
    for (int i = 0; i < 8; i++) {
        int r = (i >> 2) * 64 + ty * 4 + (i & 3);
        int m = m0 + r;
#pragma unroll
        for (int jh = 0; jh < 2; ++jh) {
            int n = n0 + jh * 64 + tx * 4;
            float4 v;
            v.x = acc[i][jh * 4 + 0] + bias[n + 0];
            v.y = acc[i][jh * 4 + 1] + bias[n + 1];
            v.z = acc[i][jh * 4 + 2] + bias[n + 2];
            v.w = acc[i][jh * 4 + 3] + bias[n + 3];
            *(float4*)&C[(size_t)m * 768 + n] = v;
        }
    }
}

// ---------------------------------------------------------------------------
extern "C" void kernel_launch(void* const* d_in, const int* in_sizes, int n_in,
                              void* d_out, int out_size, void* d_ws, size_t ws_size,
                              hipStream_t stream)
{
    const float* x    = (const float*)d_in[0];   // [2,4096,768]
    const float* Wqkv = (const float*)d_in[1];   // [768,2304]
    const float* bqkv = (const float*)d_in[2];   // [2304]
    const float* Wout = (const float*)d_in[3];   // [768,768]
    const float* bout = (const float*)d_in[4];   // [768]
    float* out = (float*)d_out;                  // [2,4096,768]

    const size_t per = (size_t)BATCH * NH * SEQ * HD;   // 6,291,456 floats
    float* ws = (float*)d_ws;
    float* Qb = ws;
    float* Kb = ws + per;
    float* Vb = ws + 2 * per;
    float* Ao = ws + 3 * per;   // [B,S,768]

    // 1) QKV projection + scatter
    gemm_qkv<<<dim3(MTOT / 128, 2304 / 128), 256, 0, stream>>>(x, Wqkv, bqkv, Qb, Kb, Vb);
    // 2) causal flash attention
    flash_attn<<<dim3(SEQ / 64, BATCH * NH), 256, 0, stream>>>(Qb, Kb, Vb, Ao);
    // 3) output projection
    gemm_out<<<dim3(MTOT / 128, 768 / 128), 256, 0, stream>>>(Ao, Wout, bout, out);
}

// Round 2
// 916.081 us; speedup vs baseline: 1.9651x; 1.9651x over previous
//
#include <hip/hip_runtime.h>
#include <hip/hip_bf16.h>
#include <math.h>

#define DIM 768
#define NH 12
#define HD 64
#define BATCH 2
#define SEQ 4096
#define MTOT (BATCH * SEQ)   // 8192

typedef unsigned short u16;
typedef __bf16 bf16x8 __attribute__((ext_vector_type(8)));
typedef float  f32x4  __attribute__((ext_vector_type(4)));
typedef unsigned short u16x4 __attribute__((ext_vector_type(4)));

__device__ inline u16 f2bf(float f) {
    unsigned u = __builtin_bit_cast(unsigned, f);
    u += 0x7fffu + ((u >> 16) & 1u);   // round-to-nearest-even
    return (u16)(u >> 16);
}

__device__ inline f32x4 mfma16(bf16x8 a, bf16x8 b, f32x4 c) {
    return __builtin_amdgcn_mfma_f32_16x16x32_bf16(a, b, c, 0, 0, 0);
}

// ---------------------------------------------------------------------------
// GEMM1: qkv[8192,2304] = x @ Wqkv + bqkv (fp32 compute), emitting bf16:
//   Q,K natural [b*NH+h][s][64]; V transposed [b*NH+h][d][s].
// ---------------------------------------------------------------------------
__global__ __launch_bounds__(256)
void gemm_qkv(const float* __restrict__ A, const float* __restrict__ W,
              const float* __restrict__ bias,
              u16* __restrict__ Qb, u16* __restrict__ Kb, u16* __restrict__ Vt)
{
    const int m0 = blockIdx.x * 128;
    const int n0 = blockIdx.y * 128;
    __shared__ float As[16][132];
    __shared__ float Bs[16][132];
    const int t  = threadIdx.x;
    const int tx = t & 15, ty = t >> 4;

    float acc[8][8];
#pragma unroll
    for (int i = 0; i < 8; i++)
#pragma unroll
        for (int j = 0; j < 8; j++) acc[i][j] = 0.f;

    for (int k0 = 0; k0 < 768; k0 += 16) {
#pragma unroll
        for (int it = 0; it < 2; ++it) {
            int fid = t + 256 * it;
            int r = fid >> 2, cq = fid & 3;
            float4 v = *(const float4*)&A[(size_t)(m0 + r) * 768 + k0 + cq * 4];
            As[cq * 4 + 0][r] = v.x;
            As[cq * 4 + 1][r] = v.y;
            As[cq * 4 + 2][r] = v.z;
            As[cq * 4 + 3][r] = v.w;
        }
#pragma unroll
        for (int it = 0; it < 2; ++it) {
            int fid = t + 256 * it;
            int r = fid >> 5, c4 = fid & 31;
            float4 v = *(const float4*)&W[(size_t)(k0 + r) * 2304 + n0 + c4 * 4];
            *(float4*)&Bs[r][c4 * 4] = v;
        }
        __syncthreads();
#pragma unroll
        for (int k = 0; k < 16; k++) {
            float4 a0 = *(float4*)&As[k][ty * 4];
            float4 a1 = *(float4*)&As[k][64 + ty * 4];
            float4 b0 = *(float4*)&Bs[k][tx * 4];
            float4 b1 = *(float4*)&Bs[k][64 + tx * 4];
            float av[8] = {a0.x, a0.y, a0.z, a0.w, a1.x, a1.y, a1.z, a1.w};
            float bv[8] = {b0.x, b0.y, b0.z, b0.w, b1.x, b1.y, b1.z, b1.w};
#pragma unroll
            for (int i = 0; i < 8; i++)
#pragma unroll
                for (int j = 0; j < 8; j++)
                    acc[i][j] += av[i] * bv[j];
        }
        __syncthreads();
    }

    const int b   = m0 >> 12;
    const int s0r = m0 & 4095;
#pragma unroll
    for (int jh = 0; jh < 2; ++jh) {
        const int nb    = n0 + jh * 64;
        const int three = nb / 768;
        const int rem   = nb - three * 768;
        const int h     = rem >> 6;
        const int d0    = tx * 4;
        float bi[4];
#pragma unroll
        for (int c = 0; c < 4; ++c) bi[c] = bias[nb + d0 + c];
        if (three < 2) {
            u16* dst = (three == 0) ? Qb : Kb;
            const size_t hb = (size_t)(b * NH + h) * SEQ;
#pragma unroll
            for (int i = 0; i < 8; ++i) {
                int r = (i >> 2) * 64 + ty * 4 + (i & 3);
                u16x4 wv;
#pragma unroll
                for (int c = 0; c < 4; ++c) wv[c] = f2bf(acc[i][jh * 4 + c] + bi[c]);
                *(u16x4*)&dst[(hb + s0r + r) * HD + d0] = wv;
            }
        } else {
            const size_t hb = (size_t)(b * NH + h) * HD;
#pragma unroll
            for (int c = 0; c < 4; ++c) {
                const size_t rowb = (hb + d0 + c) * SEQ + s0r + ty * 4;
#pragma unroll
                for (int half = 0; half < 2; ++half) {
                    u16x4 wv;
#pragma unroll
                    for (int i = 0; i < 4; ++i)
                        wv[i] = f2bf(acc[half * 4 + i][jh * 4 + c] + bi[c]);
                    *(u16x4*)&Vt[rowb + half * 64] = wv;
                }
            }
        }
    }
}

// ---------------------------------------------------------------------------
// Flash attention, bf16 MFMA (16x16x32), causal. Block = 4 waves = 64 q-rows,
// wave w owns 16 q-rows. Each block handles q-tile pair {j, 63-j} -> exactly
// 65 KV tiles per block (perfect balance). K/V fragments loaded DIRECT from
// global (no LDS, no barriers); P does a wave-private LDS round-trip
// (C-layout -> A-layout).
// ---------------------------------------------------------------------------
__global__ __launch_bounds__(256)
void flash_attn(const u16* __restrict__ Qg, const u16* __restrict__ Kg,
                const u16* __restrict__ Vtg, float* __restrict__ Og)
{
    const int pair = blockIdx.x;        // 0..31
    const int bh   = blockIdx.y;        // 0..23
    const int b    = bh / NH, h = bh % NH;
    const int t    = threadIdx.x;
    const int w    = t >> 6;
    const int lane = t & 63;
    const int quad = lane >> 4;
    const int lc   = lane & 15;

    __shared__ u16 Pl[4][16][72];       // per-wave P: [qrow16][key64], stride 72

    const u16* Qp = Qg  + (size_t)bh * SEQ * HD;
    const u16* Kp = Kg  + (size_t)bh * SEQ * HD;
    const u16* Vp = Vtg + (size_t)bh * HD * SEQ;   // [d][s]

#pragma unroll 1
    for (int half = 0; half < 2; ++half) {
        const int qt    = half ? (63 - pair) : pair;
        const int qrow0 = qt * 64 + w * 16;

        // Q A-fragments (reused for all KV tiles): A[m=lc][k=quad*8+j]
        const bf16x8 qa0 = *(const bf16x8*)&Qp[(size_t)(qrow0 + lc) * HD + quad * 8];
        const bf16x8 qa1 = *(const bf16x8*)&Qp[(size_t)(qrow0 + lc) * HD + 32 + quad * 8];

        f32x4 o[4];
        float m_r[4], l_r[4];
#pragma unroll
        for (int n = 0; n < 4; ++n) o[n] = f32x4{0.f, 0.f, 0.f, 0.f};
#pragma unroll
        for (int r = 0; r < 4; ++r) { m_r[r] = -1e30f; l_r[r] = 0.f; }

        for (int tk = 0; tk <= qt; ++tk) {
            const int kb = tk * 64;

            // ---- QK^T: S[qrow16][key64] ----
            f32x4 sacc[4];
#pragma unroll
            for (int n = 0; n < 4; ++n) sacc[n] = f32x4{0.f, 0.f, 0.f, 0.f};
#pragma unroll
            for (int n = 0; n < 4; ++n) {
                const u16* kr = &Kp[(size_t)(kb + n * 16 + lc) * HD + quad * 8];
                bf16x8 k0 = *(const bf16x8*)(kr);
                bf16x8 k1 = *(const bf16x8*)(kr + 32);
                sacc[n] = mfma16(qa0, k0, sacc[n]);
                sacc[n] = mfma16(qa1, k1, sacc[n]);
            }

            // ---- scale + causal mask (only diagonal tile) ----
            const bool diag = (tk == qt);
#pragma unroll
            for (int n = 0; n < 4; ++n) {
                const int key = kb + n * 16 + lc;
#pragma unroll
                for (int r = 0; r < 4; ++r) {
                    float v = sacc[n][r] * 0.125f;
                    if (diag && key > qrow0 + quad * 4 + r) v = -1e30f;
                    sacc[n][r] = v;
                }
            }

            // ---- online softmax (rows r = quad*4+r, cols across 16 lanes) ----
#pragma unroll
            for (int r = 0; r < 4; ++r) {
                float mx = fmaxf(fmaxf(sacc[0][r], sacc[1][r]),
                                 fmaxf(sacc[2][r], sacc[3][r]));
                mx = fmaxf(mx, __shfl_xor(mx, 1));
                mx = fmaxf(mx, __shfl_xor(mx, 2));
                mx = fmaxf(mx, __shfl_xor(mx, 4));
                mx = fmaxf(mx, __shfl_xor(mx, 8));
                const float mnew  = fmaxf(m_r[r], mx);
                const float alpha = __expf(m_r[r] - mnew);
                m_r[r] = mnew;
                float rs = 0.f;
#pragma unroll
                for (int n = 0; n < 4; ++n) {
                    float p = __expf(sacc[n][r] - mnew);
                    sacc[n][r] = p;
                    rs += p;
                }
                rs += __shfl_xor(rs, 1);
                rs += __shfl_xor(rs, 2);
                rs += __shfl_xor(rs, 4);
                rs += __shfl_xor(rs, 8);
                l_r[r] = l_r[r] * alpha + rs;
#pragma unroll
                for (int n = 0; n < 4; ++n) o[n][r] *= alpha;
                // P -> LDS in C-layout position [row=quad*4+r][col=n*16+lc]
#pragma unroll
                for (int n = 0; n < 4; ++n)
                    Pl[w][quad * 4 + r][n * 16 + lc] = f2bf(sacc[n][r]);
            }

            // ---- PV: O += P @ V ; P A-frags from LDS, V B-frags from Vt ----
            const bf16x8 pa0 = *(const bf16x8*)&Pl[w][lc][quad * 8];
            const bf16x8 pa1 = *(const bf16x8*)&Pl[w][lc][32 + quad * 8];
#pragma unroll
            for (int n = 0; n < 4; ++n) {
                const u16* vr = &Vp[(size_t)(n * 16 + lc) * SEQ + kb + quad * 8];
                bf16x8 v0 = *(const bf16x8*)(vr);
                bf16x8 v1 = *(const bf16x8*)(vr + 32);
                o[n] = mfma16(pa0, v0, o[n]);
                o[n] = mfma16(pa1, v1, o[n]);
            }
        }

        // ---- epilogue: normalize, write fp32 Ao[b][q][h*64+d] ----
#pragma unroll
        for (int r = 0; r < 4; ++r) {
            const float inv = 1.0f / l_r[r];
            const int   q   = qrow0 + quad * 4 + r;
            const size_t base = ((size_t)(b * SEQ + q)) * DIM + h * HD + lc;
            Og[base +  0] = o[0][r] * inv;
            Og[base + 16] = o[1][r] * inv;
            Og[base + 32] = o[2][r] * inv;
            Og[base + 48] = o[3][r] * inv;
        }
    }
}

// ---------------------------------------------------------------------------
// GEMM3: out[8192,768] = Ao[8192,768] @ Wout[768,768] + bout  (fp32)
// ---------------------------------------------------------------------------
__global__ __launch_bounds__(256)
void gemm_out(const float* __restrict__ A, const float* __restrict__ W,
              const float* __restrict__ bias, float* __restrict__ C)
{
    const int m0 = blockIdx.x * 128;
    const int n0 = blockIdx.y * 128;
    __shared__ float As[16][132];
    __shared__ float Bs[16][132];
    const int t  = threadIdx.x;
    const int tx = t & 15, ty = t >> 4;

    float acc[8][8];
#pragma unroll
    for (int i = 0; i < 8; i++)
#pragma unroll
        for (int j = 0; j < 8; j++) acc[i][j] = 0.f;

    for (int k0 = 0; k0 < 768; k0 += 16) {
#pragma unroll
        for (int it = 0; it < 2; ++it) {
            int fid = t + 256 * it;
            int r = fid >> 2, cq = fid & 3;
            float4 v = *(const float4*)&A[(size_t)(m0 + r) * 768 + k0 + cq * 4];
            As[cq * 4 + 0][r] = v.x;
            As[cq * 4 + 1][r] = v.y;
            As[cq * 4 + 2][r] = v.z;
            As[cq * 4 + 3][r] = v.w;
        }
#pragma unroll
        for (int it = 0; it < 2; ++it) {
            int fid = t + 256 * it;
            int r = fid >> 5, c4 = fid & 31;
            float4 v = *(const float4*)&W[(size_t)(k0 + r) * 768 + n0 + c4 * 4];
            *(float4*)&Bs[r][c4 * 4] = v;
        }
        __syncthreads();
#pragma unroll
        for (int k = 0; k < 16; k++) {
            float4 a0 = *(float4*)&As[k][ty * 4];
            float4 a1 = *(float4*)&As[k][64 + ty * 4];
            float4 b0 = *(float4*)&Bs[k][tx * 4];
            float4 b1 = *(float4*)&Bs[k][64 + tx * 4];
            float av[8] = {a0.x, a0.y, a0.z, a0.w, a1.x, a1.y, a1.z, a1.w};
            float bv[8] = {b0.x, b0.y, b0.z, b0.w, b1.x, b1.y, b1.z, b1.w};
#pragma unroll
            for (int i = 0; i < 8; i++)
#pragma unroll
                for (int j = 0; j < 8; j++)
                    acc[i][j] += av[i] * bv[j];
        }
        __syncthreads();
    }

#pragma unroll
    for (int i = 0; i < 8; i++) {
        int r = (i >> 2) * 64 + ty * 4 + (i & 3);
        int m = m0 + r;
#pragma unroll
        for (int jh = 0; jh < 2; ++jh) {
            int n = n0 + jh * 64 + tx * 4;
            float4 v;
            v.x = acc[i][jh * 4 + 0] + bias[n + 0];
            v.y = acc[i][jh * 4 + 1] + bias[n + 1];
            v.z = acc[i][jh * 4 + 2] + bias[n + 2];
            v.w = acc[i][jh * 4 + 3] + bias[n + 3];
            *(float4*)&C[(size_t)m * 768 + n] = v;
        }
    }
}

// ---------------------------------------------------------------------------
extern "C" void kernel_launch(void* const* d_in, const int* in_sizes, int n_in,
                              void* d_out, int out_size, void* d_ws, size_t ws_size,
                              hipStream_t stream)
{
    const float* x    = (const float*)d_in[0];   // [2,4096,768]
    const float* Wqkv = (const float*)d_in[1];   // [768,2304]
    const float* bqkv = (const float*)d_in[2];   // [2304]
    const float* Wout = (const float*)d_in[3];   // [768,768]
    const float* bout = (const float*)d_in[4];   // [768]
    float* out = (float*)d_out;                  // [2,4096,768]

    const size_t per = (size_t)BATCH * NH * SEQ * HD;   // 6,291,456 elements
    u16* ws16 = (u16*)d_ws;
    u16* Qb = ws16;                 // bf16 [24][4096][64]
    u16* Kb = ws16 + per;           // bf16 [24][4096][64]
    u16* Vt = ws16 + 2 * per;       // bf16 [24][64][4096]
    float* Ao = (float*)(ws16 + 3 * per);   // fp32 [2,4096,768]

    gemm_qkv<<<dim3(MTOT / 128, 2304 / 128), 256, 0, stream>>>(x, Wqkv, bqkv, Qb, Kb, Vt);
    flash_attn<<<dim3(32, BATCH * NH), 256, 0, stream>>>(Qb, Kb, Vt, Ao);
    gemm_out<<<dim3(MTOT / 128, 768 / 128), 256, 0, stream>>>(Ao, Wout, bout, out);
}

// Round 3
// 604.982 us; speedup vs baseline: 2.9756x; 1.5142x over previous
//
#include <hip/hip_runtime.h>
#include <hip/hip_bf16.h>
#include <math.h>

#define DIM 768
#define NH 12
#define HD 64
#define BATCH 2
#define SEQ 4096
#define MTOT (BATCH * SEQ)   // 8192

typedef unsigned short u16;
typedef __bf16 bf16x8 __attribute__((ext_vector_type(8)));
typedef float  f32x4  __attribute__((ext_vector_type(4)));
typedef unsigned short u16x4 __attribute__((ext_vector_type(4)));
typedef unsigned short u16x8 __attribute__((ext_vector_type(8)));

__device__ inline u16 f2bf(float f) {
    unsigned u = __builtin_bit_cast(unsigned, f);
    u += 0x7fffu + ((u >> 16) & 1u);   // round-to-nearest-even
    return (u16)(u >> 16);
}

__device__ inline f32x4 mfma16(bf16x8 a, bf16x8 b, f32x4 c) {
    return __builtin_amdgcn_mfma_f32_16x16x32_bf16(a, b, c, 0, 0, 0);
}

// ---------------------------------------------------------------------------
// fp32 -> bf16 flat copy (8 elems/thread)
// ---------------------------------------------------------------------------
__global__ __launch_bounds__(256)
void cvt_bf16(const float* __restrict__ src, u16* __restrict__ dst, int n8)
{
    int i = blockIdx.x * 256 + threadIdx.x;
    if (i >= n8) return;
    float4 a = ((const float4*)src)[i * 2];
    float4 b = ((const float4*)src)[i * 2 + 1];
    u16x8 o;
    o[0] = f2bf(a.x); o[1] = f2bf(a.y); o[2] = f2bf(a.z); o[3] = f2bf(a.w);
    o[4] = f2bf(b.x); o[5] = f2bf(b.y); o[6] = f2bf(b.z); o[7] = f2bf(b.w);
    ((u16x8*)dst)[i] = o;
}

// ---------------------------------------------------------------------------
// src[R][C] fp32 -> dst[C][R] bf16  (32x32 LDS tiles; R,C multiples of 32)
// ---------------------------------------------------------------------------
__global__ __launch_bounds__(256)
void transpose_to_bf16(const float* __restrict__ src, u16* __restrict__ dst,
                       int R, int C)
{
    __shared__ float tile[32][33];
    const int c0 = blockIdx.x * 32, r0 = blockIdx.y * 32;
    const int tx = threadIdx.x & 31, ty = threadIdx.x >> 5;   // ty: 0..7
#pragma unroll
    for (int i = 0; i < 4; ++i) {
        int row = ty * 4 + i;
        tile[row][tx] = src[(size_t)(r0 + row) * C + c0 + tx];
    }
    __syncthreads();
#pragma unroll
    for (int i = 0; i < 4; ++i) {
        int crow = ty * 4 + i;
        dst[(size_t)(c0 + crow) * R + r0 + tx] = f2bf(tile[tx][crow]);
    }
}

// ---------------------------------------------------------------------------
// bf16 MFMA GEMM mainloop: block = 4 waves, 128x128 tile; wave w covers
// 64x64 via 4x4 grid of 16x16x32 MFMAs. A[m][k], Bt[n][k], K=768.
// Fragments loaded direct from global (B tile is L2-resident across blocks).
// ---------------------------------------------------------------------------
__device__ inline void gemm_mainloop(const u16* __restrict__ A,
                                     const u16* __restrict__ Bt,
                                     int m0, int n0, int wm, int wn,
                                     int lc, int quad, f32x4 acc[4][4])
{
#pragma unroll
    for (int mi = 0; mi < 4; ++mi)
#pragma unroll
        for (int nj = 0; nj < 4; ++nj)
            acc[mi][nj] = f32x4{0.f, 0.f, 0.f, 0.f};

    const u16* Ap = A  + (size_t)(m0 + wm + lc) * 768 + quad * 8;
    const u16* Bp = Bt + (size_t)(n0 + wn + lc) * 768 + quad * 8;

#pragma unroll 2
    for (int k0 = 0; k0 < 768; k0 += 32) {
        bf16x8 af[4], bfr[4];
#pragma unroll
        for (int i = 0; i < 4; ++i) {
            af[i]  = *(const bf16x8*)(Ap + (size_t)(i * 16) * 768 + k0);
            bfr[i] = *(const bf16x8*)(Bp + (size_t)(i * 16) * 768 + k0);
        }
#pragma unroll
        for (int mi = 0; mi < 4; ++mi)
#pragma unroll
            for (int nj = 0; nj < 4; ++nj)
                acc[mi][nj] = mfma16(af[mi], bfr[nj], acc[mi][nj]);
    }
}

// ---------------------------------------------------------------------------
// GEMM1: [8192,768] @ Wqkvt[2304,768]^T + bqkv -> bf16 Q,K [bh][s][64],
// V transposed [bh][d][s].
// ---------------------------------------------------------------------------
__global__ __launch_bounds__(256)
void gemm_qkv_mfma(const u16* __restrict__ A, const u16* __restrict__ Bt,
                   const float* __restrict__ bias,
                   u16* __restrict__ Qb, u16* __restrict__ Kb, u16* __restrict__ Vt)
{
    const int m0 = blockIdx.x * 128;
    const int n0 = blockIdx.y * 128;
    const int t = threadIdx.x;
    const int w = t >> 6, lane = t & 63;
    const int quad = lane >> 4, lc = lane & 15;
    const int wm = (w & 1) * 64, wn = (w >> 1) * 64;

    f32x4 acc[4][4];
    gemm_mainloop(A, Bt, m0, n0, wm, wn, lc, quad, acc);

    const int b  = m0 >> 12;
    const int s0 = (m0 & 4095) + wm;
    const int nbase = n0 + wn;                 // multiple of 64 -> one (three,h)
    const int three = nbase / 768;
    const int rem   = nbase - three * 768;
    const int h     = rem >> 6;
    const int bh    = b * NH + h;

    if (three < 2) {
        u16* dst = (three == 0) ? Qb : Kb;
#pragma unroll
        for (int nj = 0; nj < 4; ++nj) {
            const float bi = bias[nbase + nj * 16 + lc];
            const int d = nj * 16 + lc;
#pragma unroll
            for (int mi = 0; mi < 4; ++mi) {
                const int s = s0 + mi * 16 + quad * 4;
#pragma unroll
                for (int r = 0; r < 4; ++r)
                    dst[((size_t)bh * SEQ + s + r) * HD + d] = f2bf(acc[mi][nj][r] + bi);
            }
        }
    } else {
#pragma unroll
        for (int nj = 0; nj < 4; ++nj) {
            const float bi = bias[nbase + nj * 16 + lc];
            const int d = nj * 16 + lc;
            const size_t rowb = ((size_t)bh * HD + d) * SEQ;
#pragma unroll
            for (int mi = 0; mi < 4; ++mi) {
                const int s = s0 + mi * 16 + quad * 4;
                u16x4 wv;
#pragma unroll
                for (int r = 0; r < 4; ++r) wv[r] = f2bf(acc[mi][nj][r] + bi);
                *(u16x4*)&Vt[rowb + s] = wv;
            }
        }
    }
}

// ---------------------------------------------------------------------------
// GEMM3: out[8192,768] = Ao_bf16 @ Wot[768,768]^T + bout (fp32 out)
// ---------------------------------------------------------------------------
__global__ __launch_bounds__(256)
void gemm_out_mfma(const u16* __restrict__ A, const u16* __restrict__ Bt,
                   const float* __restrict__ bias, float* __restrict__ C)
{
    const int m0 = blockIdx.x * 128;
    const int n0 = blockIdx.y * 128;
    const int t = threadIdx.x;
    const int w = t >> 6, lane = t & 63;
    const int quad = lane >> 4, lc = lane & 15;
    const int wm = (w & 1) * 64, wn = (w >> 1) * 64;

    f32x4 acc[4][4];
    gemm_mainloop(A, Bt, m0, n0, wm, wn, lc, quad, acc);

#pragma unroll
    for (int nj = 0; nj < 4; ++nj) {
        const int col = n0 + wn + nj * 16 + lc;
        const float bi = bias[col];
#pragma unroll
        for (int mi = 0; mi < 4; ++mi) {
            const int row = m0 + wm + mi * 16 + quad * 4;
#pragma unroll
            for (int r = 0; r < 4; ++r)
                C[(size_t)(row + r) * 768 + col] = acc[mi][nj][r] + bi;
        }
    }
}

// ---------------------------------------------------------------------------
// Flash attention, bf16 MFMA (16x16x32), causal — unchanged core from R2,
// except the output is written as bf16 for the downstream MFMA GEMM.
// ---------------------------------------------------------------------------
__global__ __launch_bounds__(256)
void flash_attn(const u16* __restrict__ Qg, const u16* __restrict__ Kg,
                const u16* __restrict__ Vtg, u16* __restrict__ Og)
{
    const int pair = blockIdx.x;        // 0..31
    const int bh   = blockIdx.y;        // 0..23
    const int b    = bh / NH, h = bh % NH;
    const int t    = threadIdx.x;
    const int w    = t >> 6;
    const int lane = t & 63;
    const int quad = lane >> 4;
    const int lc   = lane & 15;

    __shared__ u16 Pl[4][16][72];       // per-wave P: [qrow16][key64]

    const u16* Qp = Qg  + (size_t)bh * SEQ * HD;
    const u16* Kp = Kg  + (size_t)bh * SEQ * HD;
    const u16* Vp = Vtg + (size_t)bh * HD * SEQ;   // [d][s]

#pragma unroll 1
    for (int half = 0; half < 2; ++half) {
        const int qt    = half ? (63 - pair) : pair;
        const int qrow0 = qt * 64 + w * 16;

        const bf16x8 qa0 = *(const bf16x8*)&Qp[(size_t)(qrow0 + lc) * HD + quad * 8];
        const bf16x8 qa1 = *(const bf16x8*)&Qp[(size_t)(qrow0 + lc) * HD + 32 + quad * 8];

        f32x4 o[4];
        float m_r[4], l_r[4];
#pragma unroll
        for (int n = 0; n < 4; ++n) o[n] = f32x4{0.f, 0.f, 0.f, 0.f};
#pragma unroll
        for (int r = 0; r < 4; ++r) { m_r[r] = -1e30f; l_r[r] = 0.f; }

        for (int tk = 0; tk <= qt; ++tk) {
            const int kb = tk * 64;

            f32x4 sacc[4];
#pragma unroll
            for (int n = 0; n < 4; ++n) sacc[n] = f32x4{0.f, 0.f, 0.f, 0.f};
#pragma unroll
            for (int n = 0; n < 4; ++n) {
                const u16* kr = &Kp[(size_t)(kb + n * 16 + lc) * HD + quad * 8];
                bf16x8 k0 = *(const bf16x8*)(kr);
                bf16x8 k1 = *(const bf16x8*)(kr + 32);
                sacc[n] = mfma16(qa0, k0, sacc[n]);
                sacc[n] = mfma16(qa1, k1, sacc[n]);
            }

            const bool diag = (tk == qt);
#pragma unroll
            for (int n = 0; n < 4; ++n) {
                const int key = kb + n * 16 + lc;
#pragma unroll
                for (int r = 0; r < 4; ++r) {
                    float v = sacc[n][r] * 0.125f;
                    if (diag && key > qrow0 + quad * 4 + r) v = -1e30f;
                    sacc[n][r] = v;
                }
            }

#pragma unroll
            for (int r = 0; r < 4; ++r) {
                float mx = fmaxf(fmaxf(sacc[0][r], sacc[1][r]),
                                 fmaxf(sacc[2][r], sacc[3][r]));
                mx = fmaxf(mx, __shfl_xor(mx, 1));
                mx = fmaxf(mx, __shfl_xor(mx, 2));
                mx = fmaxf(mx, __shfl_xor(mx, 4));
                mx = fmaxf(mx, __shfl_xor(mx, 8));
                const float mnew  = fmaxf(m_r[r], mx);
                const float alpha = __expf(m_r[r] - mnew);
                m_r[r] = mnew;
                float rs = 0.f;
#pragma unroll
                for (int n = 0; n < 4; ++n) {
                    float p = __expf(sacc[n][r] - mnew);
                    sacc[n][r] = p;
                    rs += p;
                }
                rs += __shfl_xor(rs, 1);
                rs += __shfl_xor(rs, 2);
                rs += __shfl_xor(rs, 4);
                rs += __shfl_xor(rs, 8);
                l_r[r] = l_r[r] * alpha + rs;
#pragma unroll
                for (int n = 0; n < 4; ++n) o[n][r] *= alpha;
#pragma unroll
                for (int n = 0; n < 4; ++n)
                    Pl[w][quad * 4 + r][n * 16 + lc] = f2bf(sacc[n][r]);
            }

            const bf16x8 pa0 = *(const bf16x8*)&Pl[w][lc][quad * 8];
            const bf16x8 pa1 = *(const bf16x8*)&Pl[w][lc][32 + quad * 8];
#pragma unroll
            for (int n = 0; n < 4; ++n) {
                const u16* vr = &Vp[(size_t)(n * 16 + lc) * SEQ + kb + quad * 8];
                bf16x8 v0 = *(const bf16x8*)(vr);
                bf16x8 v1 = *(const bf16x8*)(vr + 32);
                o[n] = mfma16(pa0, v0, o[n]);
                o[n] = mfma16(pa1, v1, o[n]);
            }
        }

#pragma unroll
        for (int r = 0; r < 4; ++r) {
            const float inv = 1.0f / l_r[r];
            const int   q   = qrow0 + quad * 4 + r;
            const size_t base = ((size_t)(b * SEQ + q)) * DIM + h * HD + lc;
            Og[base +  0] = f2bf(o[0][r] * inv);
            Og[base + 16] = f2bf(o[1][r] * inv);
            Og[base + 32] = f2bf(o[2][r] * inv);
            Og[base + 48] = f2bf(o[3][r] * inv);
        }
    }
}

// ---------------------------------------------------------------------------
extern "C" void kernel_launch(void* const* d_in, const int* in_sizes, int n_in,
                              void* d_out, int out_size, void* d_ws, size_t ws_size,
                              hipStream_t stream)
{
    const float* x    = (const float*)d_in[0];   // [2,4096,768]
    const float* Wqkv = (const float*)d_in[1];   // [768,2304]
    const float* bqkv = (const float*)d_in[2];   // [2304]
    const float* Wout = (const float*)d_in[3];   // [768,768]
    const float* bout = (const float*)d_in[4];   // [768]
    float* out = (float*)d_out;                  // [2,4096,768]

    const size_t NX  = (size_t)MTOT * DIM;       // 6,291,456
    const size_t NWQ = (size_t)DIM * 3 * DIM;    // 1,769,472
    const size_t NWO = (size_t)DIM * DIM;        //   589,824
    u16* p   = (u16*)d_ws;
    u16* Xb  = p;              p += NX;
    u16* Wqt = p;              p += NWQ;   // [2304][768]
    u16* Wot = p;              p += NWO;   // [768][768]
    u16* Qb  = p;              p += NX;    // [24][4096][64]
    u16* Kb  = p;              p += NX;
    u16* Vt  = p;              p += NX;    // [24][64][4096]
    u16* Ao  = p;                          // bf16 [8192][768]

    cvt_bf16<<<(int)(NX / 8 + 255) / 256, 256, 0, stream>>>(x, Xb, (int)(NX / 8));
    transpose_to_bf16<<<dim3(2304 / 32, 768 / 32), 256, 0, stream>>>(Wqkv, Wqt, 768, 2304);
    transpose_to_bf16<<<dim3(768 / 32, 768 / 32), 256, 0, stream>>>(Wout, Wot, 768, 768);

    gemm_qkv_mfma<<<dim3(MTOT / 128, 2304 / 128), 256, 0, stream>>>(Xb, Wqt, bqkv, Qb, Kb, Vt);
    flash_attn<<<dim3(32, BATCH * NH), 256, 0, stream>>>(Qb, Kb, Vt, Ao);
    gemm_out_mfma<<<dim3(MTOT / 128, 768 / 128), 256, 0, stream>>>(Ao, Wot, bout, out);
}